// Round 7
// baseline (615.491 us; speedup 1.0000x reference)
//
#include <hip/hip_runtime.h>
#include <math.h>

#define NND 200000
#define NEV 100000
#define MD 100
#define TD 100
#define MSGD 172
#define NB 64
#define TILE_BYTES 61440  // 64 rows * 480 cols * 2B
#define NFRAG 25          // 400 output cols (200 rz-combined | 100 i_n | 100 h_n)
#define KS 15             // K = 480
#define BP_ELEMS (KS * NFRAG * 64 * 8)
#define GLS 72            // Gl node stride (64 + 8 pad)
#define AGS 376           // k_aggr LDS row stride (floats)

typedef __attribute__((ext_vector_type(8))) short bf16x8;
typedef __attribute__((ext_vector_type(4))) float f32x4;

__device__ __forceinline__ float sigmoidf_(float x) { return 1.0f / (1.0f + expf(-x)); }

__device__ __forceinline__ unsigned short f2bf(float f) {
    union { float f; unsigned int u; } v; v.f = f;
    unsigned int r = (v.u + 0x7FFFu + ((v.u >> 16) & 1u)) >> 16;
    return (unsigned short)r;
}
__device__ __forceinline__ float bf2f(unsigned short h) {
    union { unsigned int u; float f; } v; v.u = ((unsigned int)h) << 16;
    return v.f;
}

__device__ __forceinline__ void gload_lds16(const void* g, void* l) {
    __builtin_amdgcn_global_load_lds(
        (const __attribute__((address_space(1))) unsigned int*)g,
        (__attribute__((address_space(3))) unsigned int*)l, 16, 0, 0);
}

// ---------------- K2: count events per node ----------------
__global__ __launch_bounds__(256) void k_count(
    const int* __restrict__ src, const int* __restrict__ dst, int* __restrict__ cnt)
{
    int e = blockIdx.x * 256 + threadIdx.x;
    if (e >= NEV) return;
    atomicAdd(&cnt[src[e]], 1);
    atomicAdd(&cnt[dst[e]], 1);
}

// ---------------- K3a: per-1024-block exclusive scan ----------------
__global__ __launch_bounds__(256) void k_scan1(
    const int* __restrict__ cnt, int* __restrict__ off, int* __restrict__ psum)
{
    __shared__ int sdat[256];
    int t = threadIdx.x, b = blockIdx.x;
    int i0 = b * 1024 + t * 4;
    int v0 = (i0 + 0 < NND) ? cnt[i0 + 0] : 0;
    int v1 = (i0 + 1 < NND) ? cnt[i0 + 1] : 0;
    int v2 = (i0 + 2 < NND) ? cnt[i0 + 2] : 0;
    int v3 = (i0 + 3 < NND) ? cnt[i0 + 3] : 0;
    int tsum = v0 + v1 + v2 + v3;
    sdat[t] = tsum;
    __syncthreads();
    for (int o = 1; o < 256; o <<= 1) {
        int x = (t >= o) ? sdat[t - o] : 0;
        __syncthreads();
        sdat[t] += x;
        __syncthreads();
    }
    int excl = sdat[t] - tsum;
    if (i0 + 0 < NND) off[i0 + 0] = excl;
    if (i0 + 1 < NND) off[i0 + 1] = excl + v0;
    if (i0 + 2 < NND) off[i0 + 2] = excl + v0 + v1;
    if (i0 + 3 < NND) off[i0 + 3] = excl + v0 + v1 + v2;
    if (t == 255) psum[b] = sdat[255];
}

// ---------------- K3b: scan block sums ----------------
__global__ __launch_bounds__(256) void k_scan2(int* __restrict__ psum, int nblk)
{
    __shared__ int sdat[256];
    int t = threadIdx.x;
    int v = (t < nblk) ? psum[t] : 0;
    sdat[t] = v;
    __syncthreads();
    for (int o = 1; o < 256; o <<= 1) {
        int x = (t >= o) ? sdat[t - o] : 0;
        __syncthreads();
        sdat[t] += x;
        __syncthreads();
    }
    if (t < nblk) psum[t] = sdat[t] - v;  // exclusive
}

// ---------------- K3c: add block offsets; init cursor ----------------
__global__ __launch_bounds__(256) void k_scan3(
    int* __restrict__ off, const int* __restrict__ psum, int* __restrict__ cur)
{
    int t = threadIdx.x, b = blockIdx.x;
    int base = psum[b];
    int i0 = b * 1024 + t * 4;
#pragma unroll
    for (int j = 0; j < 4; ++j) {
        int i = i0 + j;
        if (i < NND) {
            int v = off[i] + base;
            off[i] = v;
            cur[i] = v;
        }
    }
}

// ---------------- K4: place entries (other, eid, trel, node) ----------------
__global__ __launch_bounds__(256) void k_place(
    const int* __restrict__ src, const int* __restrict__ dst,
    const int* __restrict__ tarr, const int* __restrict__ last_update,
    int* __restrict__ cur, int4* __restrict__ entries)
{
    int e = blockIdx.x * 256 + threadIdx.x;
    if (e >= NEV) return;
    int s = src[e], d = dst[e], tt = tarr[e];
    int slot = atomicAdd(&cur[s], 1);
    entries[slot] = make_int4(d, e, __float_as_int((float)(tt - last_update[s])), s);
    slot = atomicAdd(&cur[d], 1);
    entries[slot] = make_int4(s, e, __float_as_int((float)(tt - last_update[d])), d);
}

// ---------------- weight prep: combined W~ in MFMA B-fragment order ----------------
__global__ __launch_bounds__(256) void tgn_prep(
    const float* __restrict__ w_ih, const float* __restrict__ w_hh,
    unsigned short* __restrict__ Bp)
{
    int idx = blockIdx.x * 256 + threadIdx.x;
    if (idx >= BP_ELEMS) return;
    int e = idx & 7;
    int lane = (idx >> 3) & 63;
    int t = idx >> 9;          // frag id = ks*25 + nf
    int nf = t % 25;
    int ks = t / 25;
    int col = nf * 16 + (lane & 15);
    int k = ks * 32 + ((lane >> 4) << 3) + e;
    float v = 0.0f;
    if (col < 200) {
        if (k < 472) v = w_ih[col * 472 + k];
        if (k < 100) v += w_hh[col * 100 + k];
    } else if (col < 300) {
        if (k < 472) v = w_ih[col * 472 + k];
    } else {
        if (k < 100) v = w_hh[(col - 100) * 100 + k];
    }
    Bp[idx] = f2bf(v);
}

// ---------------- K_aggr: entry-parallel gather, LDS f32 accumulate ----------------
// Block owns 32 nodes; entries [off[n0], off[n0+32)) are exactly their events.
// Per entry: one wave gathers mem_other/raw_msg (coalesced f4) + computes tenc,
// ds_add_f32 into af[32][376] (dims: mem 0-99 | raw 100-271 | tenc 272-371).
__global__ __launch_bounds__(256) void k_aggr(
    const float* __restrict__ memory, const float* __restrict__ raw_msg,
    const float* __restrict__ time_w, const float* __restrict__ time_b,
    const int* __restrict__ cnt, const int* __restrict__ off,
    const int4* __restrict__ entries, unsigned short* __restrict__ agg)
{
    __shared__ __align__(16) float af[32 * AGS];
    int tid = threadIdx.x;
    int n0 = blockIdx.x * 32;

    // zero the accumulator tile
    float4 z4 = (float4){0.f, 0.f, 0.f, 0.f};
    for (int i = tid; i < 32 * AGS / 4; i += 256)
        reinterpret_cast<float4*>(af)[i] = z4;

    int wv = tid >> 6;
    int lane = tid & 63;
    int s0 = off[n0];
    int s1 = (n0 + 32 < NND) ? off[n0 + 32] : (2 * NEV);
    int m = s1 - s0;
    __syncthreads();

    const float4* tw4 = reinterpret_cast<const float4*>(time_w);
    const float4* tb4 = reinterpret_cast<const float4*>(time_b);

    int i = wv;
    int4 en_n;
    if (i < m) en_n = entries[s0 + i];
    for (; i < m; i += 4) {
        int4 en = en_n;
        if (i + 4 < m) en_n = entries[s0 + i + 4];
        float* rowp = af + (en.w - n0) * AGS;
        float trel = __int_as_float(en.z);
        if (lane < 25) {
            float4 v = reinterpret_cast<const float4*>(memory + (size_t)en.x * MD)[lane];
            atomicAdd(rowp + 4 * lane + 0, v.x);
            atomicAdd(rowp + 4 * lane + 1, v.y);
            atomicAdd(rowp + 4 * lane + 2, v.z);
            atomicAdd(rowp + 4 * lane + 3, v.w);
        }
        if (lane < 43) {
            float4 v = reinterpret_cast<const float4*>(raw_msg + (size_t)en.y * MSGD)[lane];
            atomicAdd(rowp + 100 + 4 * lane + 0, v.x);
            atomicAdd(rowp + 100 + 4 * lane + 1, v.y);
            atomicAdd(rowp + 100 + 4 * lane + 2, v.z);
            atomicAdd(rowp + 100 + 4 * lane + 3, v.w);
        }
        if (lane < 25) {
            float4 w = tw4[lane], b = tb4[lane];
            float4 v;
            v.x = cosf(trel * w.x + b.x);
            v.y = cosf(trel * w.y + b.y);
            v.z = cosf(trel * w.z + b.z);
            v.w = cosf(trel * w.w + b.w);
            atomicAdd(rowp + 272 + 4 * lane + 0, v.x);
            atomicAdd(rowp + 272 + 4 * lane + 1, v.y);
            atomicAdd(rowp + 272 + 4 * lane + 2, v.z);
            atomicAdd(rowp + 272 + 4 * lane + 3, v.w);
        }
    }
    __syncthreads();

    // write phase: thread (r = tid>>3, tsub = tid&7); same agg byte layout as before
    int r = tid >> 3, tsub = tid & 7;
    int node = n0 + r;
    int c = cnt[node];
    float ci = 1.0f / fmaxf((float)c, 1.0f);
    char* tile = reinterpret_cast<char*>(agg) + (size_t)(node >> 6) * TILE_BYTES;
    int local = node & 63;
    int rbase = local * 960;
    int swz = (local & 7) << 4;
    const float4* ms = reinterpret_cast<const float4*>(memory + (size_t)node * MD);

#pragma unroll
    for (int j = 0; j < 15; ++j) {
        int u = tsub + 8 * j;
        float4 v;
        if (u < 25) {
            v = ms[u];                       // mem_self (mean telescopes to memory[n])
        } else if (u < 118) {
            int q = u - 25;                  // af dim base = 4q (regions are contiguous)
            v.x = af[r * AGS + 4 * q + 0] * ci;
            v.y = af[r * AGS + 4 * q + 1] * ci;
            v.z = af[r * AGS + 4 * q + 2] * ci;
            v.w = af[r * AGS + 4 * q + 3] * ci;
        } else {
            v = (float4){0.f, 0.f, 0.f, 0.f};
        }
        ushort4 h;
        h.x = f2bf(v.x); h.y = f2bf(v.y); h.z = f2bf(v.z); h.w = f2bf(v.w);
        *reinterpret_cast<ushort4*>(tile + ((rbase + 8 * u) ^ swz)) = h;
    }
}

// ---------------- K_gemm: fused single-pass bf16 MFMA GRU (unchanged) ----------------
__global__ __launch_bounds__(512, 4) void tgn_gemm(
    const float* __restrict__ memory, const unsigned short* __restrict__ agg,
    const unsigned short* __restrict__ Bp,
    const float* __restrict__ b_ih, const float* __restrict__ b_hh,
    const int* __restrict__ cnt, float* __restrict__ out)
{
    __shared__ __align__(16) unsigned short lds[64 * 480];  // A tile; reused as Gl[400][72]
    __shared__ float cnt_s[NB];
    int tid = threadIdx.x;
    int n0 = blockIdx.x * NB;

    if (tid < NB) cnt_s[tid] = (float)cnt[n0 + tid];

    {
        int lane = tid & 63;
        int wv0 = tid >> 6;
        const char* gsrc = reinterpret_cast<const char*>(agg) + (size_t)blockIdx.x * TILE_BYTES;
        char* lbase = reinterpret_cast<char*>(lds);
        for (int i = wv0; i < 60; i += 8) {
            gload_lds16(gsrc + i * 1024 + lane * 16, lbase + i * 1024);
        }
    }
    __syncthreads();

    int lane = tid & 63;
    int wv = tid >> 6;
    int l15 = lane & 15;
    int kg8 = (lane >> 4) << 3;
    int f0 = (wv == 0) ? 0 : (4 + 3 * (wv - 1));
    int cw = (wv == 0) ? 4 : 3;

    f32x4 acc[4][4];
#pragma unroll
    for (int g = 0; g < 4; ++g)
#pragma unroll
        for (int i = 0; i < 4; ++i) acc[g][i] = (f32x4){0.f, 0.f, 0.f, 0.f};

    const bf16x8* BpB = reinterpret_cast<const bf16x8*>(Bp);
    const char* ldsc = reinterpret_cast<const char*>(lds);

    for (int ks = 0; ks < KS; ++ks) {
        int k0 = ks * 32 + kg8;
        const bf16x8* bp = BpB + ((size_t)(ks * NFRAG + f0)) * 64 + lane;
        bf16x8 b[4];
#pragma unroll
        for (int i = 0; i < 4; ++i)
            if (i < cw) b[i] = bp[i * 64];
#pragma unroll
        for (int g = 0; g < 4; ++g) {
            int r = g * 16 + l15;
            int ab = (r * 960 + 2 * k0) ^ ((r & 7) << 4);
            bf16x8 a = *reinterpret_cast<const bf16x8*>(ldsc + ab);
#pragma unroll
            for (int i = 0; i < 4; ++i)
                if (i < cw)
                    acc[g][i] = __builtin_amdgcn_mfma_f32_16x16x32_bf16(a, b[i], acc[g][i], 0, 0, 0);
        }
    }

    __syncthreads();  // reuse LDS as Gl[400][72] bf16

    unsigned short* Gl = lds;
    int kq = (lane >> 4) << 2;
#pragma unroll
    for (int i = 0; i < 4; ++i) {
        if (i < cw) {
            int col = (f0 + i) * 16 + l15;
            float bias = (col < 200) ? (b_ih[col] + b_hh[col])
                       : (col < 300) ? b_ih[col] : b_hh[col - 100];
#pragma unroll
            for (int g = 0; g < 4; ++g) {
                int node = g * 16 + kq;
#pragma unroll
                for (int rp = 0; rp < 2; ++rp) {
                    unsigned int lo = f2bf(acc[g][i][2 * rp] + bias);
                    unsigned int hi = f2bf(acc[g][i][2 * rp + 1] + bias);
                    *reinterpret_cast<unsigned int*>(&Gl[col * GLS + node + 2 * rp]) =
                        lo | (hi << 16);
                }
            }
        }
    }
    __syncthreads();

    for (int idx = tid; idx < NB * MD; idx += 512) {
        int n = idx / MD, j = idx - n * MD;
        float rp = bf2f(Gl[j * GLS + n]);
        float zp = bf2f(Gl[(100 + j) * GLS + n]);
        float inp = bf2f(Gl[(200 + j) * GLS + n]);
        float hnp = bf2f(Gl[(300 + j) * GLS + n]);
        float r = sigmoidf_(rp);
        float z = sigmoidf_(zp);
        float nn = tanhf(inp + r * hnp);
        float mv = memory[(size_t)(n0 + n) * MD + j];
        float h = (1.0f - z) * nn + z * mv;
        out[(size_t)(n0 + n) * MD + j] = (cnt_s[n] > 0.0f) ? h : mv;
    }
}

extern "C" void kernel_launch(void* const* d_in, const int* in_sizes, int n_in,
                              void* d_out, int out_size, void* d_ws, size_t ws_size,
                              hipStream_t stream)
{
    const float* memory      = (const float*)d_in[0];
    const float* raw_msg     = (const float*)d_in[1];
    const float* time_w      = (const float*)d_in[2];
    const float* time_b      = (const float*)d_in[3];
    const float* w_ih        = (const float*)d_in[4];
    const float* w_hh        = (const float*)d_in[5];
    const float* b_ih        = (const float*)d_in[6];
    const float* b_hh        = (const float*)d_in[7];
    const int*   last_update = (const int*)d_in[8];
    const int*   src         = (const int*)d_in[9];
    const int*   dst         = (const int*)d_in[10];
    const int*   tarr        = (const int*)d_in[11];
    float* out = (float*)d_out;

    // ws layout: cnt[N] off[N] cur[N] psum[256] | entries int4[2E] | agg bf16 | Bp
    int* cnt  = (int*)d_ws;
    int* off  = cnt + NND;
    int* cur  = off + NND;
    int* psum = cur + NND;
    int4* entries = (int4*)(psum + 256);
    unsigned short* agg = (unsigned short*)(entries + 2 * NEV);
    const int NTILE = NND / NB;  // 3125
    unsigned short* Bp = agg + (size_t)NTILE * (TILE_BYTES / 2);
    size_t need = (size_t)((char*)(Bp + BP_ELEMS) - (char*)d_ws);
    if (ws_size < need) return;

    const int NBLK = (NND + 1023) / 1024;  // 196

    hipMemsetAsync(cnt, 0, NND * sizeof(int), stream);
    tgn_prep<<<(BP_ELEMS + 255) / 256, 256, 0, stream>>>(w_ih, w_hh, Bp);
    k_count<<<(NEV + 255) / 256, 256, 0, stream>>>(src, dst, cnt);
    k_scan1<<<NBLK, 256, 0, stream>>>(cnt, off, psum);
    k_scan2<<<1, 256, 0, stream>>>(psum, NBLK);
    k_scan3<<<NBLK, 256, 0, stream>>>(off, psum, cur);
    k_place<<<(NEV + 255) / 256, 256, 0, stream>>>(src, dst, tarr, last_update, cur, entries);
    k_aggr<<<NND / 32, 256, 0, stream>>>(memory, raw_msg, time_w, time_b,
                                         cnt, off, entries, agg);
    tgn_gemm<<<NTILE, 512, 0, stream>>>(memory, agg, Bp, b_ih, b_hh, cnt, out);
}

// Round 8
// 366.276 us; speedup vs baseline: 1.6804x; 1.6804x over previous
//
#include <hip/hip_runtime.h>
#include <math.h>

#define NND 200000
#define NEV 100000
#define MD 100
#define TD 100
#define MSGD 172
#define NB 64
#define NFRAG 25          // 400 output cols (200 rz-combined | 100 i_n | 100 h_n)
#define KS 15             // K = 480
#define BP_ELEMS (KS * NFRAG * 64 * 8)
#define GLS 72            // Gl node stride (64 + 8 pad)
#define MROW 188          // msgbuf row stride in u32 (376 bf16 cols; col = dim + 4)

typedef __attribute__((ext_vector_type(8))) short bf16x8;
typedef __attribute__((ext_vector_type(4))) float f32x4;

__device__ __forceinline__ float sigmoidf_(float x) { return 1.0f / (1.0f + expf(-x)); }

__device__ __forceinline__ unsigned short f2bf(float f) {
    union { float f; unsigned int u; } v; v.f = f;
    unsigned int r = (v.u + 0x7FFFu + ((v.u >> 16) & 1u)) >> 16;
    return (unsigned short)r;
}
__device__ __forceinline__ float bf2f(unsigned int h) {
    union { unsigned int u; float f; } v; v.u = h << 16;
    return v.f;
}

// ---------------- K2: count events per node ----------------
__global__ __launch_bounds__(256) void k_count(
    const int* __restrict__ src, const int* __restrict__ dst, int* __restrict__ cnt)
{
    int e = blockIdx.x * 256 + threadIdx.x;
    if (e >= NEV) return;
    atomicAdd(&cnt[src[e]], 1);
    atomicAdd(&cnt[dst[e]], 1);
}

// ---------------- K3a: per-1024-block exclusive scan ----------------
__global__ __launch_bounds__(256) void k_scan1(
    const int* __restrict__ cnt, int* __restrict__ off, int* __restrict__ psum)
{
    __shared__ int sdat[256];
    int t = threadIdx.x, b = blockIdx.x;
    int i0 = b * 1024 + t * 4;
    int v0 = (i0 + 0 < NND) ? cnt[i0 + 0] : 0;
    int v1 = (i0 + 1 < NND) ? cnt[i0 + 1] : 0;
    int v2 = (i0 + 2 < NND) ? cnt[i0 + 2] : 0;
    int v3 = (i0 + 3 < NND) ? cnt[i0 + 3] : 0;
    int tsum = v0 + v1 + v2 + v3;
    sdat[t] = tsum;
    __syncthreads();
    for (int o = 1; o < 256; o <<= 1) {
        int x = (t >= o) ? sdat[t - o] : 0;
        __syncthreads();
        sdat[t] += x;
        __syncthreads();
    }
    int excl = sdat[t] - tsum;
    if (i0 + 0 < NND) off[i0 + 0] = excl;
    if (i0 + 1 < NND) off[i0 + 1] = excl + v0;
    if (i0 + 2 < NND) off[i0 + 2] = excl + v0 + v1;
    if (i0 + 3 < NND) off[i0 + 3] = excl + v0 + v1 + v2;
    if (t == 255) psum[b] = sdat[255];
}

// ---------------- K3b: scan block sums ----------------
__global__ __launch_bounds__(256) void k_scan2(int* __restrict__ psum, int nblk)
{
    __shared__ int sdat[256];
    int t = threadIdx.x;
    int v = (t < nblk) ? psum[t] : 0;
    sdat[t] = v;
    __syncthreads();
    for (int o = 1; o < 256; o <<= 1) {
        int x = (t >= o) ? sdat[t - o] : 0;
        __syncthreads();
        sdat[t] += x;
        __syncthreads();
    }
    if (t < nblk) psum[t] = sdat[t] - v;  // exclusive
}

// ---------------- K3c: add block offsets; init cursor ----------------
__global__ __launch_bounds__(256) void k_scan3(
    int* __restrict__ off, const int* __restrict__ psum, int* __restrict__ cur)
{
    int t = threadIdx.x, b = blockIdx.x;
    int base = psum[b];
    int i0 = b * 1024 + t * 4;
#pragma unroll
    for (int j = 0; j < 4; ++j) {
        int i = i0 + j;
        if (i < NND) {
            int v = off[i] + base;
            off[i] = v;
            cur[i] = v;
        }
    }
}

// ---------------- K4: place entries (other, eid, trel) ----------------
__global__ __launch_bounds__(256) void k_place(
    const int* __restrict__ src, const int* __restrict__ dst,
    const int* __restrict__ tarr, const int* __restrict__ last_update,
    int* __restrict__ cur, int4* __restrict__ entries)
{
    int e = blockIdx.x * 256 + threadIdx.x;
    if (e >= NEV) return;
    int s = src[e], d = dst[e], tt = tarr[e];
    int slot = atomicAdd(&cur[s], 1);
    entries[slot] = make_int4(d, e, __float_as_int((float)(tt - last_update[s])), s);
    slot = atomicAdd(&cur[d], 1);
    entries[slot] = make_int4(s, e, __float_as_int((float)(tt - last_update[d])), d);
}

// ---------------- weight prep: combined W~ in MFMA B-fragment order ----------------
__global__ __launch_bounds__(256) void tgn_prep(
    const float* __restrict__ w_ih, const float* __restrict__ w_hh,
    unsigned short* __restrict__ Bp)
{
    int idx = blockIdx.x * 256 + threadIdx.x;
    if (idx >= BP_ELEMS) return;
    int e = idx & 7;
    int lane = (idx >> 3) & 63;
    int t = idx >> 9;          // frag id = ks*25 + nf
    int nf = t % 25;
    int ks = t / 25;
    int col = nf * 16 + (lane & 15);
    int k = ks * 32 + ((lane >> 4) << 3) + e;
    float v = 0.0f;
    if (col < 200) {
        if (k < 472) v = w_ih[col * 472 + k];
        if (k < 100) v += w_hh[col * 100 + k];
    } else if (col < 300) {
        if (k < 472) v = w_ih[col * 472 + k];
    } else {
        if (k < 100) v = w_hh[(col - 100) * 100 + k];
    }
    Bp[idx] = f2bf(v);
}

// ---------------- K_msg: materialize per-slot bf16 message rows ----------------
// msgbuf[slot][376 cols], col = dim+4: dims [0,100)=mem_other, [100,272)=raw_msg,
// [272,372)=cos-enc; cols 0..3 zero.  Stored as u32 pairs (lo=even col).
__global__ __launch_bounds__(256) void k_msg(
    const float* __restrict__ memory, const float* __restrict__ raw_msg,
    const float* __restrict__ time_w, const float* __restrict__ time_b,
    const int4* __restrict__ entries, unsigned int* __restrict__ msgbuf)
{
    int tid = threadIdx.x;
    int base = blockIdx.x * 8;   // 8 slots per block
    int sl[6], p[6];
    int4 en[6];
#pragma unroll
    for (int t = 0; t < 6; ++t) {
        int idx = t * 256 + tid;       // [0,1536)
        sl[t] = idx / 192;             // 0..7
        p[t] = idx - sl[t] * 192;      // 0..191 (active < 188)
        en[t] = entries[base + sl[t]];
    }
    float2 v[6];
#pragma unroll
    for (int t = 0; t < 6; ++t) {
        float2 r; r.x = 0.f; r.y = 0.f;
        int pp = p[t];
        if (pp >= 2 && pp < 188) {
            int j0 = 2 * pp - 4;
            if (j0 < 100) {
                r = *reinterpret_cast<const float2*>(memory + (size_t)en[t].x * MD + j0);
            } else if (j0 < 272) {
                r = *reinterpret_cast<const float2*>(raw_msg + (size_t)en[t].y * MSGD + (j0 - 100));
            } else {
                int t0 = j0 - 272;
                float trel = __int_as_float(en[t].z);
                float2 w = *reinterpret_cast<const float2*>(time_w + t0);
                float2 b = *reinterpret_cast<const float2*>(time_b + t0);
                r.x = cosf(trel * w.x + b.x);
                r.y = cosf(trel * w.y + b.y);
            }
        }
        v[t] = r;
    }
#pragma unroll
    for (int t = 0; t < 6; ++t) {
        if (p[t] < 188) {
            unsigned int u = (unsigned int)f2bf(v[t].x) | ((unsigned int)f2bf(v[t].y) << 16);
            msgbuf[(size_t)(base + sl[t]) * MROW + p[t]] = u;
        }
    }
}

// ---------------- K_gemm: fused reduce-stage + bf16 MFMA GRU ----------------
// Staging: wave handles 8 nodes; lane = 16B unit u of the 960B A-row.
// u<12: mem_self k=8u..8u+7 | u==12: mem_self k96..99 + msg dims 0..3 | u in(12,59): msg | u==59: pad.
__global__ __launch_bounds__(512, 4) void tgn_gemm(
    const float* __restrict__ memory, const unsigned int* __restrict__ msgbuf,
    const unsigned short* __restrict__ Bp,
    const float* __restrict__ b_ih, const float* __restrict__ b_hh,
    const int* __restrict__ cnt, const int* __restrict__ off,
    float* __restrict__ out)
{
    __shared__ __align__(16) unsigned short lds[64 * 480];  // A tile; reused as Gl[400][72]
    __shared__ int cnt_s[NB], off_s[NB];
    int tid = threadIdx.x;
    int n0 = blockIdx.x * NB;

    if (tid < NB) {
        cnt_s[tid] = cnt[n0 + tid];
        off_s[tid] = off[n0 + tid];
    }
    __syncthreads();

    int lane = tid & 63;
    int wv = tid >> 6;

    // ---- staging: reduce msgbuf rows into swizzled bf16 A-tile ----
    {
        const uint4* mb4 = reinterpret_cast<const uint4*>(msgbuf);
        bool msgl = (lane >= 12 && lane < 59);
        int m = lane - 12;
#pragma unroll 1
        for (int r = 0; r < 8; ++r) {
            int nl = wv * 8 + r;
            int c = cnt_s[nl];
            int o0 = off_s[nl];
            float a0 = 0.f, a1 = 0.f, a2 = 0.f, a3 = 0.f;
            float a4 = 0.f, a5 = 0.f, a6 = 0.f, a7 = 0.f;
            int i = 0;
            for (; i + 1 < c; i += 2) {
                if (msgl) {
                    uint4 w0 = mb4[(size_t)(o0 + i) * 47 + m];
                    uint4 w1 = mb4[(size_t)(o0 + i + 1) * 47 + m];
                    a0 += bf2f(w0.x & 0xffffu) + bf2f(w1.x & 0xffffu);
                    a1 += bf2f(w0.x >> 16)     + bf2f(w1.x >> 16);
                    a2 += bf2f(w0.y & 0xffffu) + bf2f(w1.y & 0xffffu);
                    a3 += bf2f(w0.y >> 16)     + bf2f(w1.y >> 16);
                    a4 += bf2f(w0.z & 0xffffu) + bf2f(w1.z & 0xffffu);
                    a5 += bf2f(w0.z >> 16)     + bf2f(w1.z >> 16);
                    a6 += bf2f(w0.w & 0xffffu) + bf2f(w1.w & 0xffffu);
                    a7 += bf2f(w0.w >> 16)     + bf2f(w1.w >> 16);
                }
            }
            if (i < c && msgl) {
                uint4 w = mb4[(size_t)(o0 + i) * 47 + m];
                a0 += bf2f(w.x & 0xffffu); a1 += bf2f(w.x >> 16);
                a2 += bf2f(w.y & 0xffffu); a3 += bf2f(w.y >> 16);
                a4 += bf2f(w.z & 0xffffu); a5 += bf2f(w.z >> 16);
                a6 += bf2f(w.w & 0xffffu); a7 += bf2f(w.w >> 16);
            }
            float ci = 1.0f / fmaxf((float)c, 1.0f);
            float v0, v1, v2, v3, v4, v5, v6, v7;
            if (lane < 12) {
                const float4* ms = reinterpret_cast<const float4*>(memory + (size_t)(n0 + nl) * MD);
                float4 x = ms[2 * lane], y = ms[2 * lane + 1];
                v0 = x.x; v1 = x.y; v2 = x.z; v3 = x.w;
                v4 = y.x; v5 = y.y; v6 = y.z; v7 = y.w;
            } else if (lane == 12) {
                const float4* ms = reinterpret_cast<const float4*>(memory + (size_t)(n0 + nl) * MD);
                float4 x = ms[24];
                v0 = x.x; v1 = x.y; v2 = x.z; v3 = x.w;
                v4 = a4 * ci; v5 = a5 * ci; v6 = a6 * ci; v7 = a7 * ci;
            } else if (lane < 59) {
                v0 = a0 * ci; v1 = a1 * ci; v2 = a2 * ci; v3 = a3 * ci;
                v4 = a4 * ci; v5 = a5 * ci; v6 = a6 * ci; v7 = a7 * ci;
            } else {
                v0 = v1 = v2 = v3 = v4 = v5 = v6 = v7 = 0.f;
            }
            if (lane < 60) {
                uint4 o;
                o.x = (unsigned int)f2bf(v0) | ((unsigned int)f2bf(v1) << 16);
                o.y = (unsigned int)f2bf(v2) | ((unsigned int)f2bf(v3) << 16);
                o.z = (unsigned int)f2bf(v4) | ((unsigned int)f2bf(v5) << 16);
                o.w = (unsigned int)f2bf(v6) | ((unsigned int)f2bf(v7) << 16);
                int byte = (nl * 960 + 16 * lane) ^ ((nl & 7) << 4);
                *reinterpret_cast<uint4*>(reinterpret_cast<char*>(lds) + byte) = o;
            }
        }
    }
    __syncthreads();

    // ---- MFMA phase (unchanged from round 6) ----
    int l15 = lane & 15;
    int kg8 = (lane >> 4) << 3;
    int f0 = (wv == 0) ? 0 : (4 + 3 * (wv - 1));
    int cw = (wv == 0) ? 4 : 3;

    f32x4 acc[4][4];
#pragma unroll
    for (int g = 0; g < 4; ++g)
#pragma unroll
        for (int i = 0; i < 4; ++i) acc[g][i] = (f32x4){0.f, 0.f, 0.f, 0.f};

    const bf16x8* BpB = reinterpret_cast<const bf16x8*>(Bp);
    const char* ldsc = reinterpret_cast<const char*>(lds);

    for (int ks = 0; ks < KS; ++ks) {
        int k0 = ks * 32 + kg8;
        const bf16x8* bp = BpB + ((size_t)(ks * NFRAG + f0)) * 64 + lane;
        bf16x8 b[4];
#pragma unroll
        for (int i = 0; i < 4; ++i)
            if (i < cw) b[i] = bp[i * 64];
#pragma unroll
        for (int g = 0; g < 4; ++g) {
            int r = g * 16 + l15;
            int ab = (r * 960 + 2 * k0) ^ ((r & 7) << 4);
            bf16x8 a = *reinterpret_cast<const bf16x8*>(ldsc + ab);
#pragma unroll
            for (int i = 0; i < 4; ++i)
                if (i < cw)
                    acc[g][i] = __builtin_amdgcn_mfma_f32_16x16x32_bf16(a, b[i], acc[g][i], 0, 0, 0);
        }
    }

    __syncthreads();  // reuse LDS as Gl[400][72] bf16

    unsigned short* Gl = lds;
    int kq = (lane >> 4) << 2;
#pragma unroll
    for (int i = 0; i < 4; ++i) {
        if (i < cw) {
            int col = (f0 + i) * 16 + l15;
            float bias = (col < 200) ? (b_ih[col] + b_hh[col])
                       : (col < 300) ? b_ih[col] : b_hh[col - 100];
#pragma unroll
            for (int g = 0; g < 4; ++g) {
                int node = g * 16 + kq;
#pragma unroll
                for (int rp = 0; rp < 2; ++rp) {
                    unsigned int lo = f2bf(acc[g][i][2 * rp] + bias);
                    unsigned int hi = f2bf(acc[g][i][2 * rp + 1] + bias);
                    *reinterpret_cast<unsigned int*>(&Gl[col * GLS + node + 2 * rp]) =
                        lo | (hi << 16);
                }
            }
        }
    }
    __syncthreads();

    for (int idx = tid; idx < NB * MD; idx += 512) {
        int n = idx / MD, j = idx - n * MD;
        float rp = bf2f((unsigned int)Gl[j * GLS + n]);
        float zp = bf2f((unsigned int)Gl[(100 + j) * GLS + n]);
        float inp = bf2f((unsigned int)Gl[(200 + j) * GLS + n]);
        float hnp = bf2f((unsigned int)Gl[(300 + j) * GLS + n]);
        float r = sigmoidf_(rp);
        float z = sigmoidf_(zp);
        float nn = tanhf(inp + r * hnp);
        float mv = memory[(size_t)(n0 + n) * MD + j];
        float h = (1.0f - z) * nn + z * mv;
        out[(size_t)(n0 + n) * MD + j] = (cnt_s[n] > 0) ? h : mv;
    }
}

extern "C" void kernel_launch(void* const* d_in, const int* in_sizes, int n_in,
                              void* d_out, int out_size, void* d_ws, size_t ws_size,
                              hipStream_t stream)
{
    const float* memory      = (const float*)d_in[0];
    const float* raw_msg     = (const float*)d_in[1];
    const float* time_w      = (const float*)d_in[2];
    const float* time_b      = (const float*)d_in[3];
    const float* w_ih        = (const float*)d_in[4];
    const float* w_hh        = (const float*)d_in[5];
    const float* b_ih        = (const float*)d_in[6];
    const float* b_hh        = (const float*)d_in[7];
    const int*   last_update = (const int*)d_in[8];
    const int*   src         = (const int*)d_in[9];
    const int*   dst         = (const int*)d_in[10];
    const int*   tarr        = (const int*)d_in[11];
    float* out = (float*)d_out;

    // ws layout: cnt[N] off[N] cur[N] psum[256] | entries int4[2E] | msgbuf u32[2E*188] | Bp
    int* cnt  = (int*)d_ws;
    int* off  = cnt + NND;
    int* cur  = off + NND;
    int* psum = cur + NND;
    int4* entries = (int4*)(psum + 256);
    unsigned int* msgbuf = (unsigned int*)(entries + 2 * NEV);
    unsigned short* Bp = (unsigned short*)(msgbuf + (size_t)2 * NEV * MROW);
    size_t need = (size_t)((char*)(Bp + BP_ELEMS) - (char*)d_ws);
    if (ws_size < need) return;

    const int NBLK = (NND + 1023) / 1024;  // 196
    const int NTILE = NND / NB;            // 3125

    hipMemsetAsync(cnt, 0, NND * sizeof(int), stream);
    tgn_prep<<<(BP_ELEMS + 255) / 256, 256, 0, stream>>>(w_ih, w_hh, Bp);
    k_count<<<(NEV + 255) / 256, 256, 0, stream>>>(src, dst, cnt);
    k_scan1<<<NBLK, 256, 0, stream>>>(cnt, off, psum);
    k_scan2<<<1, 256, 0, stream>>>(psum, NBLK);
    k_scan3<<<NBLK, 256, 0, stream>>>(off, psum, cur);
    k_place<<<(NEV + 255) / 256, 256, 0, stream>>>(src, dst, tarr, last_update, cur, entries);
    k_msg<<<2 * NEV / 8, 256, 0, stream>>>(memory, raw_msg, time_w, time_b, entries, msgbuf);
    tgn_gemm<<<NTILE, 512, 0, stream>>>(memory, msgbuf, Bp, b_ih, b_hh, cnt, off, out);
}